// Round 13
// baseline (1050.079 us; speedup 1.0000x reference)
//
#include <hip/hip_runtime.h>
#include <hip/hip_bf16.h>

#define BB 16
#define CCH 64
#define HH 44
#define WWD 44
#define NSP (HH*WWD)        // 1936
#define NPAD 1984           // 31 * 64
#define NTILE 31
#define GG 4
#define GC 16
#define NELEM (BB*CCH*NSP)  // 1982464
#define EPSF 1e-5f
#define MSHIFT 20.0f        // fixed softmax shift: exp(s-M)/sum exp(s-M) == softmax(s)
#define LCHUNK 8            // j-chunks in k_lsum

typedef const float* fptr;
typedef __hip_bfloat16 bf16;
typedef __attribute__((ext_vector_type(8))) short short8;
typedef __attribute__((ext_vector_type(4))) float f32x4;

__device__ __forceinline__ float b2f(__hip_bfloat16 v) { return __bfloat162float(v); }
__device__ __forceinline__ float bflo(unsigned u) { return __uint_as_float(u << 16); }
__device__ __forceinline__ float bfhi(unsigned u) { return __uint_as_float(u & 0xFFFF0000u); }
__device__ __forceinline__ unsigned short f2bu(float f) {
    __hip_bfloat16 h = __float2bfloat16(f);
    unsigned short u; __builtin_memcpy(&u, &h, 2); return u;
}
// XOR swizzle, 8-short granularity, 64-short row: bank-conflict-free for
// b128 reads at col=quad*8 and 4/8-short writes, any row pattern.
__device__ __forceinline__ int swz(int row, int col) {
    return (row << 6) + ((((col >> 3) ^ row) & 7) << 3) + (col & 7);
}

// ---------------------------------------------------------------------------
// Kernel B1: per-(b,c) pooled stats of d = dirb(x), tile staged in LDS.
// ---------------------------------------------------------------------------
__global__ __launch_bounds__(256) void k_stats(
    fptr x, float* __restrict__ mW, float* __restrict__ xW,
    float* __restrict__ mH, float* __restrict__ xH) {
    __shared__ float tile[NSP];
    int c = blockIdx.x, b = blockIdx.y;
    int t = threadIdx.x;
    const float4* src = (const float4*)(x + ((size_t)b * CCH + c) * NSP);
    for (int e = t; e < NSP / 4; e += 256) ((float4*)tile)[e] = src[e];
    __syncthreads();
    int base = (b * CCH + c) * 44;
    if (t < HH) {
        int h = t;
        float s = 0.f, mx = -1e30f;
        for (int w = 0; w < WWD; w++) {
            float v = (w <= h) ? tile[h * WWD + w] + tile[w * WWD + (WWD - 1 - h)] : 0.f;
            s += v; mx = fmaxf(mx, v);
        }
        mW[base + h] = s * (1.f / WWD); xW[base + h] = mx;
    } else if (t >= 64 && t < 64 + WWD) {
        int w = t - 64;
        float s = 0.f, mx = -1e30f;
        for (int h = 0; h < HH; h++) {
            float v = (h >= w) ? tile[h * WWD + w] + tile[w * WWD + (WWD - 1 - h)] : 0.f;
            s += v; mx = fmaxf(mx, v);
        }
        mH[base + w] = s * (1.f / HH); xH[base + w] = mx;
    }
}

// ---------------------------------------------------------------------------
// Kernel B2: tiny shared-MLP -> sigmoid attention factors per (b,g).
// ---------------------------------------------------------------------------
__global__ __launch_bounds__(128) void k_att2(
    const float* __restrict__ mW, const float* __restrict__ xW,
    const float* __restrict__ mH, const float* __restrict__ xH,
    fptr w1p, fptr b1p, fptr bng, fptr bnb, fptr bnm, fptr bnv,
    fptr w2p, fptr b2p,
    float* __restrict__ atth, float* __restrict__ attw) {
    int bg = blockIdx.x;
    int b = bg >> 2, g = bg & 3;
    int t = threadIdx.x;
    float w1[GC], w2[GC], b2v[GC];
    for (int c = 0; c < GC; c++) { w1[c] = w1p[c]; w2[c] = w2p[c]; b2v[c] = b2p[c]; }
    float b1  = b1p[0];
    float sbn = bng[0] * rsqrtf(bnv[0] + EPSF);
    float tbn = bnb[0] - bnm[0] * sbn;
    if (t < HH) {
        int h = t;
        float zm = b1, zx = b1;
        for (int c = 0; c < GC; c++) {
            int base = (b * CCH + g * GC + c) * 44;
            zm += w1[c] * mW[base + h]; zx += w1[c] * xW[base + h];
        }
        float u = fmaxf(zm * sbn + tbn, 0.f) + fmaxf(zx * sbn + tbn, 0.f);
        for (int c = 0; c < GC; c++) {
            float a = w2[c] * u + 2.f * b2v[c];
            atth[(bg * GC + c) * HH + h] = 1.f / (1.f + __expf(-a));
        }
    } else if (t >= 64 && t < 64 + WWD) {
        int w = t - 64;
        float zm = b1, zx = b1;
        for (int c = 0; c < GC; c++) {
            int base = (b * CCH + g * GC + c) * 44;
            zm += w1[c] * mH[base + w]; zx += w1[c] * xH[base + w];
        }
        float u = fmaxf(zm * sbn + tbn, 0.f) + fmaxf(zx * sbn + tbn, 0.f);
        for (int c = 0; c < GC; c++) {
            float a = w2[c] * u + 2.f * b2v[c];
            attw[(bg * GC + c) * WWD + w] = 1.f / (1.f + __expf(-a));
        }
    }
}

// ---------------------------------------------------------------------------
// Kernel C (MFMA): p inline, 1x1 convs as GEMM.  Also zeroes lrow for k_lsum.
// ---------------------------------------------------------------------------
__global__ __launch_bounds__(256) void k_qkv_m(
    fptr x, const float* __restrict__ atth, const float* __restrict__ attw,
    fptr wq, fptr bq, fptr wk, fptr bk, fptr wv, fptr bv,
    bf16* __restrict__ qT, bf16* __restrict__ kT, bf16* __restrict__ vC,
    float* __restrict__ lrow) {
    __shared__ unsigned short pTile[64 * 64];
    __shared__ unsigned short xTile[64 * 64];
    int t = threadIdx.x;
    int b = blockIdx.y;
    int p0 = blockIdx.x * 64;
    {
        int lin = (blockIdx.y * gridDim.x + blockIdx.x) * 256 + t;
        if (lin < BB * NPAD) lrow[lin] = 0.f;
    }
    {
        int px = t & 63, c4base = t >> 6;
        int p = p0 + px;
        bool valid = (p < NSP);
        int h = valid ? p / WWD : 0, w = valid ? p % WWD : 0;
        fptr xB = x + (size_t)b * CCH * NSP;
        #pragma unroll
        for (int it = 0; it < 4; it++) {
            int c4 = c4base + it * 4;
            unsigned pk0 = 0, pk1 = 0, xk0 = 0, xk1 = 0;
            #pragma unroll
            for (int jj = 0; jj < 4; jj++) {
                int c = c4 * 4 + jj;
                float xvv = 0.f, pvv = 0.f;
                if (valid) {
                    xvv = xB[(size_t)c * NSP + p];
                    if (h >= w) pvv = xvv + xB[(size_t)c * NSP + w * WWD + (WWD - 1 - h)];
                    int gi = (b * GG + (c >> 4)) * GC + (c & 15);
                    pvv *= atth[gi * HH + h] * attw[gi * WWD + w];
                }
                unsigned pu = f2bu(pvv), xu = f2bu(xvv);
                if (jj < 2) { pk0 |= pu << (16 * jj);        xk0 |= xu << (16 * jj); }
                else        { pk1 |= pu << (16 * (jj - 2));  xk1 |= xu << (16 * (jj - 2)); }
            }
            *(uint2*)&pTile[swz(px, c4 * 4)] = (uint2){pk0, pk1};
            *(uint2*)&xTile[swz(px, c4 * 4)] = (uint2){xk0, xk1};
        }
    }
    int wave = t >> 6, lane = t & 63, lo = lane & 15, quad = lane >> 4;
    int o = wave * 16 + lo;
    short8 aq[2], ak[2], av[2];
    #pragma unroll
    for (int hf = 0; hf < 2; hf++) {
        fptr sq = wq + (size_t)o * 64 + hf * 32 + quad * 8;
        fptr sk = wk + (size_t)o * 64 + hf * 32 + quad * 8;
        fptr sv = wv + (size_t)o * 64 + hf * 32 + quad * 8;
        short8 a, k2, v2;
        #pragma unroll
        for (int j = 0; j < 8; j++) {
            a[j]  = (short)f2bu(sq[j]);
            k2[j] = (short)f2bu(sk[j]);
            v2[j] = (short)f2bu(sv[j]);
        }
        aq[hf] = a; ak[hf] = k2; av[hf] = v2;
    }
    float bqv[4], bkv[4], bvv[4];
    #pragma unroll
    for (int r = 0; r < 4; r++) {
        int o2 = wave * 16 + quad * 4 + r;
        bqv[r] = bq[o2]; bkv[r] = bk[o2]; bvv[r] = bv[o2];
    }
    __syncthreads();
    #pragma unroll
    for (int js = 0; js < 4; js++) {
        int prow = js * 16 + lo;
        short8 pb0 = *(const short8*)&pTile[swz(prow, quad * 8)];
        short8 pb1 = *(const short8*)&pTile[swz(prow, 32 + quad * 8)];
        short8 xb0 = *(const short8*)&xTile[swz(prow, quad * 8)];
        short8 xb1 = *(const short8*)&xTile[swz(prow, 32 + quad * 8)];
        f32x4 sq = {0.f,0.f,0.f,0.f}, sk = sq, sv = sq;
        sq = __builtin_amdgcn_mfma_f32_16x16x32_bf16(aq[0], pb0, sq, 0, 0, 0);
        sq = __builtin_amdgcn_mfma_f32_16x16x32_bf16(aq[1], pb1, sq, 0, 0, 0);
        sk = __builtin_amdgcn_mfma_f32_16x16x32_bf16(ak[0], pb0, sk, 0, 0, 0);
        sk = __builtin_amdgcn_mfma_f32_16x16x32_bf16(ak[1], pb1, sk, 0, 0, 0);
        sv = __builtin_amdgcn_mfma_f32_16x16x32_bf16(av[0], xb0, sv, 0, 0, 0);
        sv = __builtin_amdgcn_mfma_f32_16x16x32_bf16(av[1], xb1, sv, 0, 0, 0);
        int p = p0 + js * 16 + lo;
        size_t rowbase = ((size_t)b * NPAD + p) * 64 + wave * 16 + quad * 4;
        if (p < NSP) {
            uint2 pq, pk;
            pq.x = (unsigned)f2bu(sq[0]+bqv[0]) | ((unsigned)f2bu(sq[1]+bqv[1]) << 16);
            pq.y = (unsigned)f2bu(sq[2]+bqv[2]) | ((unsigned)f2bu(sq[3]+bqv[3]) << 16);
            pk.x = (unsigned)f2bu(sk[0]+bkv[0]) | ((unsigned)f2bu(sk[1]+bkv[1]) << 16);
            pk.y = (unsigned)f2bu(sk[2]+bkv[2]) | ((unsigned)f2bu(sk[3]+bkv[3]) << 16);
            *(uint2*)(qT + rowbase) = pq;
            *(uint2*)(kT + rowbase) = pk;
            #pragma unroll
            for (int r = 0; r < 4; r++) {
                int oc = wave * 16 + quad * 4 + r;
                vC[(size_t)b * 64 * NPAD + (size_t)oc * NPAD + p] = __float2bfloat16(sv[r] + bvv[r]);
            }
        } else {
            *(uint2*)(qT + rowbase) = (uint2){0, 0};
            *(uint2*)(kT + rowbase) = (uint2){0, 0};
            #pragma unroll
            for (int r = 0; r < 4; r++) {
                int oc = wave * 16 + quad * 4 + r;
                vC[(size_t)b * 64 * NPAD + (size_t)oc * NPAD + p] = __float2bfloat16(0.f);
            }
        }
    }
}

// ---------------------------------------------------------------------------
// Kernel D1 (MFMA): lrow_i += partial sum_j exp(s_ij - MSHIFT) over a j-chunk.
// LDS k-tiles, double-buffered, swizzled.
// ---------------------------------------------------------------------------
__global__ __launch_bounds__(256) void k_lsum(
    const bf16* __restrict__ qT, const bf16* __restrict__ kT,
    float* __restrict__ lrow) {
    __shared__ unsigned short kt[2][64 * 64];
    int t = threadIdx.x;
    int wave = t >> 6, lane = t & 63, lo = lane & 15, quad = lane >> 4;
    int b = blockIdx.z;
    int chunk = blockIdx.y;
    int i0 = blockIdx.x * 64;
    const bf16* qB = qT + (size_t)b * NPAD * 64;
    const bf16* kB = kT + (size_t)b * NPAD * 64;
    int irow = i0 + wave * 16 + lo;
    short8 qf0 = *(const short8*)(qB + (size_t)irow * 64 + quad * 8);
    short8 qf1 = *(const short8*)(qB + (size_t)irow * 64 + 32 + quad * 8);
    float l[4] = {0.f, 0.f, 0.f, 0.f};
    {
        const uint4* src = (const uint4*)(kB + (size_t)chunk * 64 * 64);
        #pragma unroll
        for (int it = 0; it < 2; it++) {
            int e = t + it * 256;
            *(uint4*)&kt[0][swz(e >> 3, (e & 7) * 8)] = src[e];
        }
    }
    __syncthreads();
    int buf = 0;
    for (int jt = chunk; jt < NTILE; jt += LCHUNK) {
        int jn = jt + LCHUNK;
        if (jn < NTILE) {
            const uint4* src = (const uint4*)(kB + (size_t)jn * 64 * 64);
            #pragma unroll
            for (int it = 0; it < 2; it++) {
                int e = t + it * 256;
                *(uint4*)&kt[buf ^ 1][swz(e >> 3, (e & 7) * 8)] = src[e];
            }
        }
        #pragma unroll
        for (int js = 0; js < 4; js++) {
            short8 kf0 = *(const short8*)&kt[buf][swz(js * 16 + lo, quad * 8)];
            short8 kf1 = *(const short8*)&kt[buf][swz(js * 16 + lo, 32 + quad * 8)];
            f32x4 s = {0.f, 0.f, 0.f, 0.f};
            s = __builtin_amdgcn_mfma_f32_16x16x32_bf16(qf0, kf0, s, 0, 0, 0);
            s = __builtin_amdgcn_mfma_f32_16x16x32_bf16(qf1, kf1, s, 0, 0, 0);
            bool valid = (jt * 64 + js * 16 + lo < NSP);
            #pragma unroll
            for (int r = 0; r < 4; r++) {
                float e = __expf(s[r] - MSHIFT);
                l[r] += valid ? e : 0.f;
            }
        }
        __syncthreads();
        buf ^= 1;
    }
    #pragma unroll
    for (int d = 1; d < 16; d <<= 1) {
        #pragma unroll
        for (int r = 0; r < 4; r++) l[r] += __shfl_xor(l[r], d, 64);
    }
    if (lo == 0) {
        #pragma unroll
        for (int r = 0; r < 4; r++) {
            int ig = i0 + wave * 16 + quad * 4 + r;
            atomicAdd(&lrow[(size_t)b * NPAD + ig], l[r]);
        }
    }
}

// ---------------------------------------------------------------------------
// Kernel D1b: vC[b][c][i] *= 1/lrow[b][i]  (pre-normalized V -> attout needs
// no per-row scale at all).  Coalesced uint2 per thread.
// ---------------------------------------------------------------------------
__global__ __launch_bounds__(256) void k_vscale(
    bf16* __restrict__ vC, const float* __restrict__ lrow) {
    int b = blockIdx.y;
    int idx = blockIdx.x * 256 + threadIdx.x;      // 64*NPAD/4 = 31744 quads
    int i4 = (idx % (NPAD / 4)) * 4;
    int c  = idx / (NPAD / 4);
    float4 l4 = *(const float4*)(lrow + (size_t)b * NPAD + i4);
    bf16* p = vC + (size_t)b * 64 * NPAD + (size_t)c * NPAD + i4;
    uint2 v = *(uint2*)p;
    float v0 = bflo(v.x) * __builtin_amdgcn_rcpf(l4.x);
    float v1 = bfhi(v.x) * __builtin_amdgcn_rcpf(l4.y);
    float v2 = bflo(v.y) * __builtin_amdgcn_rcpf(l4.z);
    float v3 = bfhi(v.y) * __builtin_amdgcn_rcpf(l4.w);
    uint2 o;
    o.x = (unsigned)f2bu(v0) | ((unsigned)f2bu(v1) << 16);
    o.y = (unsigned)f2bu(v2) | ((unsigned)f2bu(v3) << 16);
    *(uint2*)p = o;
}

// ---------------------------------------------------------------------------
// Kernel D2 (MFMA): aoP[b][p][c] = sum_i exp(s_ij - MSHIFT) * V'[c,i]
// (V' pre-normalized).  Swizzled E-tile; depth-2 register prefetch pipeline:
// loads for iter it+2 issued during iter it, covered by a full iter body.
// ---------------------------------------------------------------------------
__global__ __launch_bounds__(256) void k_attout(
    const bf16* __restrict__ qT, const bf16* __restrict__ kT,
    const bf16* __restrict__ vC,
    bf16* __restrict__ aoP) {
    __shared__ unsigned short Elds[64 * 64];
    int t = threadIdx.x;
    int wave = t >> 6, lane = t & 63, lo = lane & 15, quad = lane >> 4;
    int b = blockIdx.y;
    int j0 = blockIdx.x * 64;
    const bf16* qB = qT + (size_t)b * NPAD * 64;
    const bf16* kB = kT + (size_t)b * NPAD * 64;
    const bf16* vB = vC + (size_t)b * 64 * NPAD;
    short8 kf[4][2];
    #pragma unroll
    for (int js = 0; js < 4; js++) {
        const bf16* kr = kB + (size_t)(j0 + js * 16 + lo) * 64;
        kf[js][0] = *(const short8*)(kr + quad * 8);
        kf[js][1] = *(const short8*)(kr + 32 + quad * 8);
    }
    f32x4 acc[4];
    #pragma unroll
    for (int js = 0; js < 4; js++) acc[js] = (f32x4){0.f, 0.f, 0.f, 0.f};
    const bf16* vrowb = vB + (size_t)(wave * 16 + lo) * NPAD;
    // preload iters 0 and 1 (NTILE >= 2)
    short8 qfr[2][2], vfr[2][2];
    #pragma unroll
    for (int pp = 0; pp < 2; pp++) {
        const bf16* qr = qB + (size_t)(pp * 64 + wave * 16 + lo) * 64;
        qfr[pp][0] = *(const short8*)(qr + quad * 8);
        qfr[pp][1] = *(const short8*)(qr + 32 + quad * 8);
        const bf16* vr = vrowb + pp * 64;
        vfr[pp][0] = *(const short8*)(vr + quad * 8);
        vfr[pp][1] = *(const short8*)(vr + 32 + quad * 8);
    }
    for (int it = 0; it < NTILE; it++) {
        int p = it & 1;
        // step B: S = q.k, E = exp(S - M)  -> swizzled LDS
        #pragma unroll
        for (int js = 0; js < 4; js++) {
            f32x4 s = {0.f, 0.f, 0.f, 0.f};
            s = __builtin_amdgcn_mfma_f32_16x16x32_bf16(qfr[p][0], kf[js][0], s, 0, 0, 0);
            s = __builtin_amdgcn_mfma_f32_16x16x32_bf16(qfr[p][1], kf[js][1], s, 0, 0, 0);
            float e0 = __expf(s[0] - MSHIFT);
            float e1 = __expf(s[1] - MSHIFT);
            float e2 = __expf(s[2] - MSHIFT);
            float e3 = __expf(s[3] - MSHIFT);
            uint2 pk;
            pk.x = (unsigned)f2bu(e0) | ((unsigned)f2bu(e1) << 16);
            pk.y = (unsigned)f2bu(e2) | ((unsigned)f2bu(e3) << 16);
            *(uint2*)&Elds[swz(js * 16 + lo, wave * 16 + quad * 4)] = pk;
        }
        __syncthreads();
        // q-prefetch for it+2 (qfr[p] fully consumed by step B above);
        // latency covered by step C + all of iter it+1.
        if (it + 2 < NTILE) {
            const bf16* qr = qB + (size_t)((it + 2) * 64 + wave * 16 + lo) * 64;
            qfr[p][0] = *(const short8*)(qr + quad * 8);
            qfr[p][1] = *(const short8*)(qr + 32 + quad * 8);
        }
        // step C: acc += V' . E
        #pragma unroll
        for (int js = 0; js < 4; js++) {
            short8 ef0 = *(const short8*)&Elds[swz(js * 16 + lo, quad * 8)];
            short8 ef1 = *(const short8*)&Elds[swz(js * 16 + lo, 32 + quad * 8)];
            acc[js] = __builtin_amdgcn_mfma_f32_16x16x32_bf16(vfr[p][0], ef0, acc[js], 0, 0, 0);
            acc[js] = __builtin_amdgcn_mfma_f32_16x16x32_bf16(vfr[p][1], ef1, acc[js], 0, 0, 0);
        }
        // v-prefetch for it+2 (vfr[p] consumed by step C above)
        if (it + 2 < NTILE) {
            const bf16* vr = vrowb + (it + 2) * 64;
            vfr[p][0] = *(const short8*)(vr + quad * 8);
            vfr[p][1] = *(const short8*)(vr + 32 + quad * 8);
        }
        __syncthreads();
    }
    #pragma unroll
    for (int js = 0; js < 4; js++) {
        int j = j0 + js * 16 + lo;
        if (j < NSP) {
            uint2 pk;
            pk.x = (unsigned)f2bu(acc[js][0]) | ((unsigned)f2bu(acc[js][1]) << 16);
            pk.y = (unsigned)f2bu(acc[js][2]) | ((unsigned)f2bu(acc[js][3]) << 16);
            *(uint2*)(aoP + ((size_t)b * NSP + j) * 64 + wave * 16 + quad * 4) = pk;
        }
    }
}

// ---------------------------------------------------------------------------
// Kernel E (MFMA, fused): 3x3 conv + BN + ReLU -> LDS -> 1x1 conv + BN + ReLU
// + gamma*y + x -> f32 out.  One block per (64-px tile, b).
// ---------------------------------------------------------------------------
__global__ __launch_bounds__(256) void k_conv3f(
    const bf16* __restrict__ aoP, fptr c3w,
    fptr g3, fptr b3, fptr m3, fptr v3,
    fptr c1w, fptr g1, fptr b1, fptr m1, fptr v1, fptr gamma,
    fptr x, float* __restrict__ out) {
    __shared__ unsigned short tile[5 * 46 * 72];   // 33120 B halo tile
    __shared__ unsigned short yT[64 * 64];         // 8 KB conv output (swizzled)
    __shared__ float sbn[64], tbn[64];
    int t = threadIdx.x;
    int b = blockIdx.y, pt = blockIdx.x;
    int p0 = pt * 64;
    int hbase = p0 / 44 - 1;
    // stage halo tile (zero-padded)
    for (int task = t; task < 230 * 2; task += 256) {
        int l = task >> 1, half = task & 1;
        int r = l / 46, cidx = l % 46;
        int h = hbase + r, w = cidx - 1;
        uint4 v0 = {0,0,0,0}, v1_ = v0, v2 = v0, v3_ = v0;
        if ((unsigned)h < HH && (unsigned)w < WWD) {
            const uint4* src = (const uint4*)(aoP + ((size_t)b * NSP + h * WWD + w) * 64 + half * 32);
            v0 = src[0]; v1_ = src[1]; v2 = src[2]; v3_ = src[3];
        }
        uint4* dst = (uint4*)(tile + l * 72 + half * 32);
        dst[0] = v0; dst[1] = v1_; dst[2] = v2; dst[3] = v3_;
    }
    if (t < 64) {
        float s = g3[t] * rsqrtf(v3[t] + EPSF);
        sbn[t] = s; tbn[t] = b3[t] - m3[t] * s;
    }
    int wave = t >> 6, lane = t & 63, lo = lane & 15, quad = lane >> 4;
    int co = wave * 16 + lo;
    // conv weight A-frags
    short8 af[9][2];
    #pragma unroll
    for (int tap = 0; tap < 9; tap++) {
        #pragma unroll
        for (int hf = 0; hf < 2; hf++) {
            short8 a;
            #pragma unroll
            for (int j = 0; j < 8; j++) {
                int ci = quad * 8 + j + 32 * hf;
                a[j] = (short)f2bu(c3w[(size_t)co * 576 + ci * 9 + tap]);
            }
            af[tap][hf] = a;
        }
    }
    // 1x1 weight A-frags + BN2 + gamma (loaded early, used after 2nd barrier)
    short8 af2[2];
    #pragma unroll
    for (int hf = 0; hf < 2; hf++) {
        fptr sw = c1w + (size_t)co * 64 + hf * 32 + quad * 8;
        short8 a;
        #pragma unroll
        for (int j = 0; j < 8; j++) a[j] = (short)f2bu(sw[j]);
        af2[hf] = a;
    }
    float sbv[4], tbv[4];
    #pragma unroll
    for (int r = 0; r < 4; r++) {
        int c = wave * 16 + quad * 4 + r;
        float s = g1[c] * rsqrtf(v1[c] + EPSF);
        sbv[r] = s; tbv[r] = b1[c] - m1[c] * s;
    }
    float gam = gamma[0];
    __syncthreads();
    // 3x3 conv via MFMA
    f32x4 acc[4];
    #pragma unroll
    for (int js = 0; js < 4; js++) acc[js] = (f32x4){0.f, 0.f, 0.f, 0.f};
    #pragma unroll
    for (int js = 0; js < 4; js++) {
        int p = p0 + js * 16 + lo;
        int h = p / WWD, w = p % WWD;
        int rb = h - hbase, wb = w + 1;
        #pragma unroll
        for (int tap = 0; tap < 9; tap++) {
            int dh = tap / 3 - 1, dw = tap % 3 - 1;
            const unsigned short* src = tile + ((rb + dh) * 46 + (wb + dw)) * 72;
            short8 b0 = *(const short8*)(src + quad * 8);
            short8 b1_ = *(const short8*)(src + 32 + quad * 8);
            acc[js] = __builtin_amdgcn_mfma_f32_16x16x32_bf16(af[tap][0], b0, acc[js], 0, 0, 0);
            acc[js] = __builtin_amdgcn_mfma_f32_16x16x32_bf16(af[tap][1], b1_, acc[js], 0, 0, 0);
        }
    }
    // BN + ReLU -> swizzled LDS (y tile, [px][c])
    #pragma unroll
    for (int js = 0; js < 4; js++) {
        float o[4];
        #pragma unroll
        for (int r = 0; r < 4; r++) {
            int c = wave * 16 + quad * 4 + r;
            o[r] = fmaxf(acc[js][r] * sbn[c] + tbn[c], 0.f);
        }
        uint2 pk;
        pk.x = (unsigned)f2bu(o[0]) | ((unsigned)f2bu(o[1]) << 16);
        pk.y = (unsigned)f2bu(o[2]) | ((unsigned)f2bu(o[3]) << 16);
        *(uint2*)&yT[swz(js * 16 + lo, wave * 16 + quad * 4)] = pk;
    }
    __syncthreads();
    // 1x1 conv + BN + ReLU + residual
    #pragma unroll
    for (int js = 0; js < 4; js++) {
        short8 e0 = *(const short8*)&yT[swz(js * 16 + lo, quad * 8)];
        short8 e1 = *(const short8*)&yT[swz(js * 16 + lo, 32 + quad * 8)];
        f32x4 a2 = {0.f, 0.f, 0.f, 0.f};
        a2 = __builtin_amdgcn_mfma_f32_16x16x32_bf16(af2[0], e0, a2, 0, 0, 0);
        a2 = __builtin_amdgcn_mfma_f32_16x16x32_bf16(af2[1], e1, a2, 0, 0, 0);
        int p = p0 + js * 16 + lo;
        if (p < NSP) {
            #pragma unroll
            for (int r = 0; r < 4; r++) {
                int c = wave * 16 + quad * 4 + r;
                float val = fmaxf(a2[r] * sbv[r] + tbv[r], 0.f);
                out[((size_t)b * CCH + c) * NSP + p] = gam * val + x[((size_t)b * CCH + c) * NSP + p];
            }
        }
    }
}

// ---------------------------------------------------------------------------
extern "C" void kernel_launch(void* const* d_in, const int* in_sizes, int n_in,
                              void* d_out, int out_size, void* d_ws, size_t ws_size,
                              hipStream_t stream) {
    fptr x      = (fptr)d_in[0];
    fptr sg_w1  = (fptr)d_in[1];
    fptr sg_b1  = (fptr)d_in[2];
    fptr sg_bng = (fptr)d_in[3];
    fptr sg_bnb = (fptr)d_in[4];
    fptr sg_bnm = (fptr)d_in[5];
    fptr sg_bnv = (fptr)d_in[6];
    fptr sg_w2  = (fptr)d_in[7];
    fptr sg_b2  = (fptr)d_in[8];
    fptr wq     = (fptr)d_in[9];
    fptr bq     = (fptr)d_in[10];
    fptr wk     = (fptr)d_in[11];
    fptr bk     = (fptr)d_in[12];
    fptr wv     = (fptr)d_in[13];
    fptr bv     = (fptr)d_in[14];
    fptr gamma  = (fptr)d_in[15];
    fptr c3w    = (fptr)d_in[16];
    fptr c3g    = (fptr)d_in[17];
    fptr c3b    = (fptr)d_in[18];
    fptr c3m    = (fptr)d_in[19];
    fptr c3v    = (fptr)d_in[20];
    fptr c1w    = (fptr)d_in[21];
    fptr c1g    = (fptr)d_in[22];
    fptr c1b    = (fptr)d_in[23];
    fptr c1m    = (fptr)d_in[24];
    fptr c1v    = (fptr)d_in[25];

    bf16*  qT    = (bf16*)d_ws;                      // [b][NPAD][64]
    bf16*  kT    = qT + (size_t)BB * NPAD * 64;      // [b][NPAD][64]
    bf16*  vC    = kT + (size_t)BB * NPAD * 64;      // [b][64][NPAD]
    bf16*  aoP   = vC + (size_t)BB * NPAD * 64;      // [b][NSP][64] pixel-major
    float* atth  = (float*)(aoP + (size_t)BB * NSP * 64);
    float* attw  = atth + BB*GG*GC*HH;
    float* lrow  = attw + BB*GG*GC*WWD;              // [b][NPAD]
    float* mWs   = lrow + (size_t)BB * NPAD;         // stats: 4 x [b][c][44]
    float* xWs   = mWs + BB*CCH*44;
    float* mHs   = xWs + BB*CCH*44;
    float* xHs   = mHs + BB*CCH*44;

    k_stats<<<dim3(CCH, BB), 256, 0, stream>>>(x, mWs, xWs, mHs, xHs);
    k_att2<<<BB * GG, 128, 0, stream>>>(mWs, xWs, mHs, xHs,
                                        sg_w1, sg_b1, sg_bng, sg_bnb,
                                        sg_bnm, sg_bnv, sg_w2, sg_b2, atth, attw);
    k_qkv_m<<<dim3(NTILE, BB), 256, 0, stream>>>(x, atth, attw, wq, bq, wk, bk, wv, bv,
                                                 qT, kT, vC, lrow);
    k_lsum<<<dim3(NTILE, LCHUNK, BB), 256, 0, stream>>>(qT, kT, lrow);
    k_vscale<<<dim3(64 * NPAD / 4 / 256, BB), 256, 0, stream>>>(vC, lrow);
    k_attout<<<dim3(NTILE, BB), 256, 0, stream>>>(qT, kT, vC, aoP);
    k_conv3f<<<dim3(NTILE, BB), 256, 0, stream>>>(aoP, c3w, c3g, c3b, c3m, c3v,
                                                  c1w, c1g, c1b, c1m, c1v, gamma,
                                                  x, (float*)d_out);
}

// Round 14
// 214.512 us; speedup vs baseline: 4.8952x; 4.8952x over previous
//
#include <hip/hip_runtime.h>
#include <hip/hip_bf16.h>

#define BB 16
#define CCH 64
#define HH 44
#define WWD 44
#define NSP (HH*WWD)        // 1936
#define NPAD 1984           // 31 * 64
#define NTILE 31
#define GG 4
#define GC 16
#define NELEM (BB*CCH*NSP)  // 1982464
#define EPSF 1e-5f
#define MSHIFT 20.0f        // fixed softmax shift: exp(s-M)/sum exp(s-M) == softmax(s)
#define LCHUNK 8            // j-chunks in k_lsum

typedef const float* fptr;
typedef __hip_bfloat16 bf16;
typedef __attribute__((ext_vector_type(8))) short short8;
typedef __attribute__((ext_vector_type(4))) float f32x4;

__device__ __forceinline__ float b2f(__hip_bfloat16 v) { return __bfloat162float(v); }
__device__ __forceinline__ float bflo(unsigned u) { return __uint_as_float(u << 16); }
__device__ __forceinline__ float bfhi(unsigned u) { return __uint_as_float(u & 0xFFFF0000u); }
__device__ __forceinline__ unsigned short f2bu(float f) {
    __hip_bfloat16 h = __float2bfloat16(f);
    unsigned short u; __builtin_memcpy(&u, &h, 2); return u;
}
// XOR swizzle, 8-short granularity, 64-short row: bank-conflict-free for
// b128 reads at col=quad*8 and 4/8-short writes, any row pattern.
__device__ __forceinline__ int swz(int row, int col) {
    return (row << 6) + ((((col >> 3) ^ row) & 7) << 3) + (col & 7);
}

// ---------------------------------------------------------------------------
// Kernel B1: per-(b,c) pooled stats of d = dirb(x), tile staged in LDS.
// ---------------------------------------------------------------------------
__global__ __launch_bounds__(256) void k_stats(
    fptr x, float* __restrict__ mW, float* __restrict__ xW,
    float* __restrict__ mH, float* __restrict__ xH) {
    __shared__ float tile[NSP];
    int c = blockIdx.x, b = blockIdx.y;
    int t = threadIdx.x;
    const float4* src = (const float4*)(x + ((size_t)b * CCH + c) * NSP);
    for (int e = t; e < NSP / 4; e += 256) ((float4*)tile)[e] = src[e];
    __syncthreads();
    int base = (b * CCH + c) * 44;
    if (t < HH) {
        int h = t;
        float s = 0.f, mx = -1e30f;
        for (int w = 0; w < WWD; w++) {
            float v = (w <= h) ? tile[h * WWD + w] + tile[w * WWD + (WWD - 1 - h)] : 0.f;
            s += v; mx = fmaxf(mx, v);
        }
        mW[base + h] = s * (1.f / WWD); xW[base + h] = mx;
    } else if (t >= 64 && t < 64 + WWD) {
        int w = t - 64;
        float s = 0.f, mx = -1e30f;
        for (int h = 0; h < HH; h++) {
            float v = (h >= w) ? tile[h * WWD + w] + tile[w * WWD + (WWD - 1 - h)] : 0.f;
            s += v; mx = fmaxf(mx, v);
        }
        mH[base + w] = s * (1.f / HH); xH[base + w] = mx;
    }
}

// ---------------------------------------------------------------------------
// Kernel B2: tiny shared-MLP -> sigmoid attention factors per (b,g).
// ---------------------------------------------------------------------------
__global__ __launch_bounds__(128) void k_att2(
    const float* __restrict__ mW, const float* __restrict__ xW,
    const float* __restrict__ mH, const float* __restrict__ xH,
    fptr w1p, fptr b1p, fptr bng, fptr bnb, fptr bnm, fptr bnv,
    fptr w2p, fptr b2p,
    float* __restrict__ atth, float* __restrict__ attw) {
    int bg = blockIdx.x;
    int b = bg >> 2, g = bg & 3;
    int t = threadIdx.x;
    float w1[GC], w2[GC], b2v[GC];
    for (int c = 0; c < GC; c++) { w1[c] = w1p[c]; w2[c] = w2p[c]; b2v[c] = b2p[c]; }
    float b1  = b1p[0];
    float sbn = bng[0] * rsqrtf(bnv[0] + EPSF);
    float tbn = bnb[0] - bnm[0] * sbn;
    if (t < HH) {
        int h = t;
        float zm = b1, zx = b1;
        for (int c = 0; c < GC; c++) {
            int base = (b * CCH + g * GC + c) * 44;
            zm += w1[c] * mW[base + h]; zx += w1[c] * xW[base + h];
        }
        float u = fmaxf(zm * sbn + tbn, 0.f) + fmaxf(zx * sbn + tbn, 0.f);
        for (int c = 0; c < GC; c++) {
            float a = w2[c] * u + 2.f * b2v[c];
            atth[(bg * GC + c) * HH + h] = 1.f / (1.f + __expf(-a));
        }
    } else if (t >= 64 && t < 64 + WWD) {
        int w = t - 64;
        float zm = b1, zx = b1;
        for (int c = 0; c < GC; c++) {
            int base = (b * CCH + g * GC + c) * 44;
            zm += w1[c] * mH[base + w]; zx += w1[c] * xH[base + w];
        }
        float u = fmaxf(zm * sbn + tbn, 0.f) + fmaxf(zx * sbn + tbn, 0.f);
        for (int c = 0; c < GC; c++) {
            float a = w2[c] * u + 2.f * b2v[c];
            attw[(bg * GC + c) * WWD + w] = 1.f / (1.f + __expf(-a));
        }
    }
}

// ---------------------------------------------------------------------------
// Kernel C (MFMA): p inline, 1x1 convs as GEMM.  Also zeroes lrow for k_lsum.
// ---------------------------------------------------------------------------
__global__ __launch_bounds__(256) void k_qkv_m(
    fptr x, const float* __restrict__ atth, const float* __restrict__ attw,
    fptr wq, fptr bq, fptr wk, fptr bk, fptr wv, fptr bv,
    bf16* __restrict__ qT, bf16* __restrict__ kT, bf16* __restrict__ vC,
    float* __restrict__ lrow) {
    __shared__ unsigned short pTile[64 * 64];
    __shared__ unsigned short xTile[64 * 64];
    int t = threadIdx.x;
    int b = blockIdx.y;
    int p0 = blockIdx.x * 64;
    {
        int lin = (blockIdx.y * gridDim.x + blockIdx.x) * 256 + t;
        if (lin < BB * NPAD) lrow[lin] = 0.f;
    }
    {
        int px = t & 63, c4base = t >> 6;
        int p = p0 + px;
        bool valid = (p < NSP);
        int h = valid ? p / WWD : 0, w = valid ? p % WWD : 0;
        fptr xB = x + (size_t)b * CCH * NSP;
        #pragma unroll
        for (int it = 0; it < 4; it++) {
            int c4 = c4base + it * 4;
            unsigned pk0 = 0, pk1 = 0, xk0 = 0, xk1 = 0;
            #pragma unroll
            for (int jj = 0; jj < 4; jj++) {
                int c = c4 * 4 + jj;
                float xvv = 0.f, pvv = 0.f;
                if (valid) {
                    xvv = xB[(size_t)c * NSP + p];
                    if (h >= w) pvv = xvv + xB[(size_t)c * NSP + w * WWD + (WWD - 1 - h)];
                    int gi = (b * GG + (c >> 4)) * GC + (c & 15);
                    pvv *= atth[gi * HH + h] * attw[gi * WWD + w];
                }
                unsigned pu = f2bu(pvv), xu = f2bu(xvv);
                if (jj < 2) { pk0 |= pu << (16 * jj);        xk0 |= xu << (16 * jj); }
                else        { pk1 |= pu << (16 * (jj - 2));  xk1 |= xu << (16 * (jj - 2)); }
            }
            *(uint2*)&pTile[swz(px, c4 * 4)] = (uint2){pk0, pk1};
            *(uint2*)&xTile[swz(px, c4 * 4)] = (uint2){xk0, xk1};
        }
    }
    int wave = t >> 6, lane = t & 63, lo = lane & 15, quad = lane >> 4;
    int o = wave * 16 + lo;
    short8 aq[2], ak[2], av[2];
    #pragma unroll
    for (int hf = 0; hf < 2; hf++) {
        fptr sq = wq + (size_t)o * 64 + hf * 32 + quad * 8;
        fptr sk = wk + (size_t)o * 64 + hf * 32 + quad * 8;
        fptr sv = wv + (size_t)o * 64 + hf * 32 + quad * 8;
        short8 a, k2, v2;
        #pragma unroll
        for (int j = 0; j < 8; j++) {
            a[j]  = (short)f2bu(sq[j]);
            k2[j] = (short)f2bu(sk[j]);
            v2[j] = (short)f2bu(sv[j]);
        }
        aq[hf] = a; ak[hf] = k2; av[hf] = v2;
    }
    float bqv[4], bkv[4], bvv[4];
    #pragma unroll
    for (int r = 0; r < 4; r++) {
        int o2 = wave * 16 + quad * 4 + r;
        bqv[r] = bq[o2]; bkv[r] = bk[o2]; bvv[r] = bv[o2];
    }
    __syncthreads();
    #pragma unroll
    for (int js = 0; js < 4; js++) {
        int prow = js * 16 + lo;
        short8 pb0 = *(const short8*)&pTile[swz(prow, quad * 8)];
        short8 pb1 = *(const short8*)&pTile[swz(prow, 32 + quad * 8)];
        short8 xb0 = *(const short8*)&xTile[swz(prow, quad * 8)];
        short8 xb1 = *(const short8*)&xTile[swz(prow, 32 + quad * 8)];
        f32x4 sq = {0.f,0.f,0.f,0.f}, sk = sq, sv = sq;
        sq = __builtin_amdgcn_mfma_f32_16x16x32_bf16(aq[0], pb0, sq, 0, 0, 0);
        sq = __builtin_amdgcn_mfma_f32_16x16x32_bf16(aq[1], pb1, sq, 0, 0, 0);
        sk = __builtin_amdgcn_mfma_f32_16x16x32_bf16(ak[0], pb0, sk, 0, 0, 0);
        sk = __builtin_amdgcn_mfma_f32_16x16x32_bf16(ak[1], pb1, sk, 0, 0, 0);
        sv = __builtin_amdgcn_mfma_f32_16x16x32_bf16(av[0], xb0, sv, 0, 0, 0);
        sv = __builtin_amdgcn_mfma_f32_16x16x32_bf16(av[1], xb1, sv, 0, 0, 0);
        int p = p0 + js * 16 + lo;
        size_t rowbase = ((size_t)b * NPAD + p) * 64 + wave * 16 + quad * 4;
        if (p < NSP) {
            uint2 pq, pk;
            pq.x = (unsigned)f2bu(sq[0]+bqv[0]) | ((unsigned)f2bu(sq[1]+bqv[1]) << 16);
            pq.y = (unsigned)f2bu(sq[2]+bqv[2]) | ((unsigned)f2bu(sq[3]+bqv[3]) << 16);
            pk.x = (unsigned)f2bu(sk[0]+bkv[0]) | ((unsigned)f2bu(sk[1]+bkv[1]) << 16);
            pk.y = (unsigned)f2bu(sk[2]+bkv[2]) | ((unsigned)f2bu(sk[3]+bkv[3]) << 16);
            *(uint2*)(qT + rowbase) = pq;
            *(uint2*)(kT + rowbase) = pk;
            #pragma unroll
            for (int r = 0; r < 4; r++) {
                int oc = wave * 16 + quad * 4 + r;
                vC[(size_t)b * 64 * NPAD + (size_t)oc * NPAD + p] = __float2bfloat16(sv[r] + bvv[r]);
            }
        } else {
            *(uint2*)(qT + rowbase) = (uint2){0, 0};
            *(uint2*)(kT + rowbase) = (uint2){0, 0};
            #pragma unroll
            for (int r = 0; r < 4; r++) {
                int oc = wave * 16 + quad * 4 + r;
                vC[(size_t)b * 64 * NPAD + (size_t)oc * NPAD + p] = __float2bfloat16(0.f);
            }
        }
    }
}

// ---------------------------------------------------------------------------
// Kernel D1 (MFMA): lrow_i += partial sum_j exp(s_ij - MSHIFT) over a j-chunk.
// LDS k-tiles, double-buffered, swizzled.
// ---------------------------------------------------------------------------
__global__ __launch_bounds__(256) void k_lsum(
    const bf16* __restrict__ qT, const bf16* __restrict__ kT,
    float* __restrict__ lrow) {
    __shared__ unsigned short kt[2][64 * 64];
    int t = threadIdx.x;
    int wave = t >> 6, lane = t & 63, lo = lane & 15, quad = lane >> 4;
    int b = blockIdx.z;
    int chunk = blockIdx.y;
    int i0 = blockIdx.x * 64;
    const bf16* qB = qT + (size_t)b * NPAD * 64;
    const bf16* kB = kT + (size_t)b * NPAD * 64;
    int irow = i0 + wave * 16 + lo;
    short8 qf0 = *(const short8*)(qB + (size_t)irow * 64 + quad * 8);
    short8 qf1 = *(const short8*)(qB + (size_t)irow * 64 + 32 + quad * 8);
    float l[4] = {0.f, 0.f, 0.f, 0.f};
    {
        const uint4* src = (const uint4*)(kB + (size_t)chunk * 64 * 64);
        #pragma unroll
        for (int it = 0; it < 2; it++) {
            int e = t + it * 256;
            *(uint4*)&kt[0][swz(e >> 3, (e & 7) * 8)] = src[e];
        }
    }
    __syncthreads();
    int buf = 0;
    for (int jt = chunk; jt < NTILE; jt += LCHUNK) {
        int jn = jt + LCHUNK;
        if (jn < NTILE) {
            const uint4* src = (const uint4*)(kB + (size_t)jn * 64 * 64);
            #pragma unroll
            for (int it = 0; it < 2; it++) {
                int e = t + it * 256;
                *(uint4*)&kt[buf ^ 1][swz(e >> 3, (e & 7) * 8)] = src[e];
            }
        }
        #pragma unroll
        for (int js = 0; js < 4; js++) {
            short8 kf0 = *(const short8*)&kt[buf][swz(js * 16 + lo, quad * 8)];
            short8 kf1 = *(const short8*)&kt[buf][swz(js * 16 + lo, 32 + quad * 8)];
            f32x4 s = {0.f, 0.f, 0.f, 0.f};
            s = __builtin_amdgcn_mfma_f32_16x16x32_bf16(qf0, kf0, s, 0, 0, 0);
            s = __builtin_amdgcn_mfma_f32_16x16x32_bf16(qf1, kf1, s, 0, 0, 0);
            bool valid = (jt * 64 + js * 16 + lo < NSP);
            #pragma unroll
            for (int r = 0; r < 4; r++) {
                float e = __expf(s[r] - MSHIFT);
                l[r] += valid ? e : 0.f;
            }
        }
        __syncthreads();
        buf ^= 1;
    }
    #pragma unroll
    for (int d = 1; d < 16; d <<= 1) {
        #pragma unroll
        for (int r = 0; r < 4; r++) l[r] += __shfl_xor(l[r], d, 64);
    }
    if (lo == 0) {
        #pragma unroll
        for (int r = 0; r < 4; r++) {
            int ig = i0 + wave * 16 + quad * 4 + r;
            atomicAdd(&lrow[(size_t)b * NPAD + ig], l[r]);
        }
    }
}

// ---------------------------------------------------------------------------
// Kernel D1b: vC[b][c][i] *= 1/lrow[b][i]  (pre-normalized V -> attout needs
// no per-row scale at all).  Coalesced uint2 per thread.
// ---------------------------------------------------------------------------
__global__ __launch_bounds__(256) void k_vscale(
    bf16* __restrict__ vC, const float* __restrict__ lrow) {
    int b = blockIdx.y;
    int idx = blockIdx.x * 256 + threadIdx.x;      // 64*NPAD/4 = 31744 quads
    int i4 = (idx % (NPAD / 4)) * 4;
    int c  = idx / (NPAD / 4);
    float4 l4 = *(const float4*)(lrow + (size_t)b * NPAD + i4);
    bf16* p = vC + (size_t)b * 64 * NPAD + (size_t)c * NPAD + i4;
    uint2 v = *(uint2*)p;
    float v0 = bflo(v.x) * __builtin_amdgcn_rcpf(l4.x);
    float v1 = bfhi(v.x) * __builtin_amdgcn_rcpf(l4.y);
    float v2 = bflo(v.y) * __builtin_amdgcn_rcpf(l4.z);
    float v3 = bfhi(v.y) * __builtin_amdgcn_rcpf(l4.w);
    uint2 o;
    o.x = (unsigned)f2bu(v0) | ((unsigned)f2bu(v1) << 16);
    o.y = (unsigned)f2bu(v2) | ((unsigned)f2bu(v3) << 16);
    *(uint2*)p = o;
}

// ---------------------------------------------------------------------------
// Kernel D2 (MFMA): aoP[b][p][c] = sum_i exp(s_ij - MSHIFT) * V'[c,i]
// (V' pre-normalized).  Swizzled E-tile; depth-2 prefetch with STATIC register
// sets (loop unrolled x2 — round 13's dynamic-index array spilled to scratch).
// ---------------------------------------------------------------------------
#define ATT_BODY(QF0, QF1, VF0, VF1, PF_IT)                                         \
    {                                                                               \
        _Pragma("unroll")                                                           \
        for (int js = 0; js < 4; js++) {                                            \
            f32x4 s = {0.f, 0.f, 0.f, 0.f};                                         \
            s = __builtin_amdgcn_mfma_f32_16x16x32_bf16(QF0, kf[js][0], s, 0, 0, 0);\
            s = __builtin_amdgcn_mfma_f32_16x16x32_bf16(QF1, kf[js][1], s, 0, 0, 0);\
            uint2 pk;                                                               \
            pk.x = (unsigned)f2bu(__expf(s[0] - MSHIFT)) |                          \
                   ((unsigned)f2bu(__expf(s[1] - MSHIFT)) << 16);                   \
            pk.y = (unsigned)f2bu(__expf(s[2] - MSHIFT)) |                          \
                   ((unsigned)f2bu(__expf(s[3] - MSHIFT)) << 16);                   \
            *(uint2*)&Elds[swz(js * 16 + lo, wave * 16 + quad * 4)] = pk;           \
        }                                                                           \
        __syncthreads();                                                            \
        if ((PF_IT) < NTILE) {                                                      \
            const bf16* qr = qB + (size_t)((PF_IT) * 64 + wave * 16 + lo) * 64;     \
            QF0 = *(const short8*)(qr + quad * 8);                                  \
            QF1 = *(const short8*)(qr + 32 + quad * 8);                             \
        }                                                                           \
        _Pragma("unroll")                                                           \
        for (int js = 0; js < 4; js++) {                                            \
            short8 ef0 = *(const short8*)&Elds[swz(js * 16 + lo, quad * 8)];        \
            short8 ef1 = *(const short8*)&Elds[swz(js * 16 + lo, 32 + quad * 8)];   \
            acc[js] = __builtin_amdgcn_mfma_f32_16x16x32_bf16(VF0, ef0, acc[js], 0, 0, 0); \
            acc[js] = __builtin_amdgcn_mfma_f32_16x16x32_bf16(VF1, ef1, acc[js], 0, 0, 0); \
        }                                                                           \
        if ((PF_IT) < NTILE) {                                                      \
            const bf16* vr = vrowb + (PF_IT) * 64;                                  \
            VF0 = *(const short8*)(vr + quad * 8);                                  \
            VF1 = *(const short8*)(vr + 32 + quad * 8);                             \
        }                                                                           \
        __syncthreads();                                                            \
    }

__global__ __launch_bounds__(256) void k_attout(
    const bf16* __restrict__ qT, const bf16* __restrict__ kT,
    const bf16* __restrict__ vC,
    bf16* __restrict__ aoP) {
    __shared__ unsigned short Elds[64 * 64];
    int t = threadIdx.x;
    int wave = t >> 6, lane = t & 63, lo = lane & 15, quad = lane >> 4;
    int b = blockIdx.y;
    int j0 = blockIdx.x * 64;
    const bf16* qB = qT + (size_t)b * NPAD * 64;
    const bf16* kB = kT + (size_t)b * NPAD * 64;
    const bf16* vB = vC + (size_t)b * 64 * NPAD;
    short8 kf[4][2];
    #pragma unroll
    for (int js = 0; js < 4; js++) {
        const bf16* kr = kB + (size_t)(j0 + js * 16 + lo) * 64;
        kf[js][0] = *(const short8*)(kr + quad * 8);
        kf[js][1] = *(const short8*)(kr + 32 + quad * 8);
    }
    f32x4 acc[4];
    #pragma unroll
    for (int js = 0; js < 4; js++) acc[js] = (f32x4){0.f, 0.f, 0.f, 0.f};
    const bf16* vrowb = vB + (size_t)(wave * 16 + lo) * NPAD;
    // preload iter 0 -> set A, iter 1 -> set B (static registers)
    short8 qa0, qa1, va0, va1, qb0, qb1, vb0, vb1;
    {
        const bf16* qr = qB + (size_t)(wave * 16 + lo) * 64;
        qa0 = *(const short8*)(qr + quad * 8);
        qa1 = *(const short8*)(qr + 32 + quad * 8);
        va0 = *(const short8*)(vrowb + quad * 8);
        va1 = *(const short8*)(vrowb + 32 + quad * 8);
        const bf16* qr2 = qB + (size_t)(64 + wave * 16 + lo) * 64;
        qb0 = *(const short8*)(qr2 + quad * 8);
        qb1 = *(const short8*)(qr2 + 32 + quad * 8);
        const bf16* vr2 = vrowb + 64;
        vb0 = *(const short8*)(vr2 + quad * 8);
        vb1 = *(const short8*)(vr2 + 32 + quad * 8);
    }
    // 15 pairs (iters 0..29), then epilogue iter 30 on set A
    for (int it2 = 0; it2 + 1 < NTILE; it2 += 2) {
        ATT_BODY(qa0, qa1, va0, va1, it2 + 2);
        ATT_BODY(qb0, qb1, vb0, vb1, it2 + 3);
    }
    ATT_BODY(qa0, qa1, va0, va1, NTILE);   // it = 30, no prefetch
    #pragma unroll
    for (int js = 0; js < 4; js++) {
        int j = j0 + js * 16 + lo;
        if (j < NSP) {
            uint2 pk;
            pk.x = (unsigned)f2bu(acc[js][0]) | ((unsigned)f2bu(acc[js][1]) << 16);
            pk.y = (unsigned)f2bu(acc[js][2]) | ((unsigned)f2bu(acc[js][3]) << 16);
            *(uint2*)(aoP + ((size_t)b * NSP + j) * 64 + wave * 16 + quad * 4) = pk;
        }
    }
}

// ---------------------------------------------------------------------------
// Kernel E (MFMA, fused): 3x3 conv + BN + ReLU -> LDS -> 1x1 conv + BN + ReLU
// + gamma*y + x -> f32 out.  One block per (64-px tile, b).
// ---------------------------------------------------------------------------
__global__ __launch_bounds__(256) void k_conv3f(
    const bf16* __restrict__ aoP, fptr c3w,
    fptr g3, fptr b3, fptr m3, fptr v3,
    fptr c1w, fptr g1, fptr b1, fptr m1, fptr v1, fptr gamma,
    fptr x, float* __restrict__ out) {
    __shared__ unsigned short tile[5 * 46 * 72];   // 33120 B halo tile
    __shared__ unsigned short yT[64 * 64];         // 8 KB conv output (swizzled)
    __shared__ float sbn[64], tbn[64];
    int t = threadIdx.x;
    int b = blockIdx.y, pt = blockIdx.x;
    int p0 = pt * 64;
    int hbase = p0 / 44 - 1;
    // stage halo tile (zero-padded)
    for (int task = t; task < 230 * 2; task += 256) {
        int l = task >> 1, half = task & 1;
        int r = l / 46, cidx = l % 46;
        int h = hbase + r, w = cidx - 1;
        uint4 v0 = {0,0,0,0}, v1_ = v0, v2 = v0, v3_ = v0;
        if ((unsigned)h < HH && (unsigned)w < WWD) {
            const uint4* src = (const uint4*)(aoP + ((size_t)b * NSP + h * WWD + w) * 64 + half * 32);
            v0 = src[0]; v1_ = src[1]; v2 = src[2]; v3_ = src[3];
        }
        uint4* dst = (uint4*)(tile + l * 72 + half * 32);
        dst[0] = v0; dst[1] = v1_; dst[2] = v2; dst[3] = v3_;
    }
    if (t < 64) {
        float s = g3[t] * rsqrtf(v3[t] + EPSF);
        sbn[t] = s; tbn[t] = b3[t] - m3[t] * s;
    }
    int wave = t >> 6, lane = t & 63, lo = lane & 15, quad = lane >> 4;
    int co = wave * 16 + lo;
    // conv weight A-frags
    short8 af[9][2];
    #pragma unroll
    for (int tap = 0; tap < 9; tap++) {
        #pragma unroll
        for (int hf = 0; hf < 2; hf++) {
            short8 a;
            #pragma unroll
            for (int j = 0; j < 8; j++) {
                int ci = quad * 8 + j + 32 * hf;
                a[j] = (short)f2bu(c3w[(size_t)co * 576 + ci * 9 + tap]);
            }
            af[tap][hf] = a;
        }
    }
    // 1x1 weight A-frags + BN2 + gamma (loaded early, used after 2nd barrier)
    short8 af2[2];
    #pragma unroll
    for (int hf = 0; hf < 2; hf++) {
        fptr sw = c1w + (size_t)co * 64 + hf * 32 + quad * 8;
        short8 a;
        #pragma unroll
        for (int j = 0; j < 8; j++) a[j] = (short)f2bu(sw[j]);
        af2[hf] = a;
    }
    float sbv[4], tbv[4];
    #pragma unroll
    for (int r = 0; r < 4; r++) {
        int c = wave * 16 + quad * 4 + r;
        float s = g1[c] * rsqrtf(v1[c] + EPSF);
        sbv[r] = s; tbv[r] = b1[c] - m1[c] * s;
    }
    float gam = gamma[0];
    __syncthreads();
    // 3x3 conv via MFMA
    f32x4 acc[4];
    #pragma unroll
    for (int js = 0; js < 4; js++) acc[js] = (f32x4){0.f, 0.f, 0.f, 0.f};
    #pragma unroll
    for (int js = 0; js < 4; js++) {
        int p = p0 + js * 16 + lo;
        int h = p / WWD, w = p % WWD;
        int rb = h - hbase, wb = w + 1;
        #pragma unroll
        for (int tap = 0; tap < 9; tap++) {
            int dh = tap / 3 - 1, dw = tap % 3 - 1;
            const unsigned short* src = tile + ((rb + dh) * 46 + (wb + dw)) * 72;
            short8 b0 = *(const short8*)(src + quad * 8);
            short8 b1_ = *(const short8*)(src + 32 + quad * 8);
            acc[js] = __builtin_amdgcn_mfma_f32_16x16x32_bf16(af[tap][0], b0, acc[js], 0, 0, 0);
            acc[js] = __builtin_amdgcn_mfma_f32_16x16x32_bf16(af[tap][1], b1_, acc[js], 0, 0, 0);
        }
    }
    // BN + ReLU -> swizzled LDS (y tile, [px][c])
    #pragma unroll
    for (int js = 0; js < 4; js++) {
        float o[4];
        #pragma unroll
        for (int r = 0; r < 4; r++) {
            int c = wave * 16 + quad * 4 + r;
            o[r] = fmaxf(acc[js][r] * sbn[c] + tbn[c], 0.f);
        }
        uint2 pk;
        pk.x = (unsigned)f2bu(o[0]) | ((unsigned)f2bu(o[1]) << 16);
        pk.y = (unsigned)f2bu(o[2]) | ((unsigned)f2bu(o[3]) << 16);
        *(uint2*)&yT[swz(js * 16 + lo, wave * 16 + quad * 4)] = pk;
    }
    __syncthreads();
    // 1x1 conv + BN + ReLU + residual
    #pragma unroll
    for (int js = 0; js < 4; js++) {
        short8 e0 = *(const short8*)&yT[swz(js * 16 + lo, quad * 8)];
        short8 e1 = *(const short8*)&yT[swz(js * 16 + lo, 32 + quad * 8)];
        f32x4 a2 = {0.f, 0.f, 0.f, 0.f};
        a2 = __builtin_amdgcn_mfma_f32_16x16x32_bf16(af2[0], e0, a2, 0, 0, 0);
        a2 = __builtin_amdgcn_mfma_f32_16x16x32_bf16(af2[1], e1, a2, 0, 0, 0);
        int p = p0 + js * 16 + lo;
        if (p < NSP) {
            #pragma unroll
            for (int r = 0; r < 4; r++) {
                int c = wave * 16 + quad * 4 + r;
                float val = fmaxf(a2[r] * sbv[r] + tbv[r], 0.f);
                out[((size_t)b * CCH + c) * NSP + p] = gam * val + x[((size_t)b * CCH + c) * NSP + p];
            }
        }
    }
}

// ---------------------------------------------------------------------------
extern "C" void kernel_launch(void* const* d_in, const int* in_sizes, int n_in,
                              void* d_out, int out_size, void* d_ws, size_t ws_size,
                              hipStream_t stream) {
    fptr x      = (fptr)d_in[0];
    fptr sg_w1  = (fptr)d_in[1];
    fptr sg_b1  = (fptr)d_in[2];
    fptr sg_bng = (fptr)d_in[3];
    fptr sg_bnb = (fptr)d_in[4];
    fptr sg_bnm = (fptr)d_in[5];
    fptr sg_bnv = (fptr)d_in[6];
    fptr sg_w2  = (fptr)d_in[7];
    fptr sg_b2  = (fptr)d_in[8];
    fptr wq     = (fptr)d_in[9];
    fptr bq     = (fptr)d_in[10];
    fptr wk     = (fptr)d_in[11];
    fptr bk     = (fptr)d_in[12];
    fptr wv     = (fptr)d_in[13];
    fptr bv     = (fptr)d_in[14];
    fptr gamma  = (fptr)d_in[15];
    fptr c3w    = (fptr)d_in[16];
    fptr c3g    = (fptr)d_in[17];
    fptr c3b    = (fptr)d_in[18];
    fptr c3m    = (fptr)d_in[19];
    fptr c3v    = (fptr)d_in[20];
    fptr c1w    = (fptr)d_in[21];
    fptr c1g    = (fptr)d_in[22];
    fptr c1b    = (fptr)d_in[23];
    fptr c1m    = (fptr)d_in[24];
    fptr c1v    = (fptr)d_in[25];

    bf16*  qT    = (bf16*)d_ws;                      // [b][NPAD][64]
    bf16*  kT    = qT + (size_t)BB * NPAD * 64;      // [b][NPAD][64]
    bf16*  vC    = kT + (size_t)BB * NPAD * 64;      // [b][64][NPAD]
    bf16*  aoP   = vC + (size_t)BB * NPAD * 64;      // [b][NSP][64] pixel-major
    float* atth  = (float*)(aoP + (size_t)BB * NSP * 64);
    float* attw  = atth + BB*GG*GC*HH;
    float* lrow  = attw + BB*GG*GC*WWD;              // [b][NPAD]
    float* mWs   = lrow + (size_t)BB * NPAD;         // stats: 4 x [b][c][44]
    float* xWs   = mWs + BB*CCH*44;
    float* mHs   = xWs + BB*CCH*44;
    float* xHs   = mHs + BB*CCH*44;

    k_stats<<<dim3(CCH, BB), 256, 0, stream>>>(x, mWs, xWs, mHs, xHs);
    k_att2<<<BB * GG, 128, 0, stream>>>(mWs, xWs, mHs, xHs,
                                        sg_w1, sg_b1, sg_bng, sg_bnb,
                                        sg_bnm, sg_bnv, sg_w2, sg_b2, atth, attw);
    k_qkv_m<<<dim3(NTILE, BB), 256, 0, stream>>>(x, atth, attw, wq, bq, wk, bk, wv, bv,
                                                 qT, kT, vC, lrow);
    k_lsum<<<dim3(NTILE, LCHUNK, BB), 256, 0, stream>>>(qT, kT, lrow);
    k_vscale<<<dim3(64 * NPAD / 4 / 256, BB), 256, 0, stream>>>(vC, lrow);
    k_attout<<<dim3(NTILE, BB), 256, 0, stream>>>(qT, kT, vC, aoP);
    k_conv3f<<<dim3(NTILE, BB), 256, 0, stream>>>(aoP, c3w, c3g, c3b, c3m, c3v,
                                                  c1w, c1g, c1b, c1m, c1v, gamma,
                                                  x, (float*)d_out);
}